// Round 1
// baseline (504.206 us; speedup 1.0000x reference)
//
#include <hip/hip_runtime.h>
#include <hip/hip_bf16.h>

typedef __bf16 bf16_t;
typedef __bf16 bf16x8 __attribute__((ext_vector_type(8)));
typedef float f32x4 __attribute__((ext_vector_type(4)));

#define HIDDEN 2048
#define NHEADS 16
#define HD 128
#define NTOK 2048
#define BATCH 2
#define MROWS (BATCH*NTOK)
#define QKVCOLS (3*HIDDEN)

__device__ __forceinline__ void gload16(const void* g, void* l) {
    __builtin_amdgcn_global_load_lds(
        (const __attribute__((address_space(1))) void*)g,
        (__attribute__((address_space(3))) void*)l,
        16, 0, 0);
}

// ---------------- fp32 -> bf16 elementwise (x) ----------------
__global__ __launch_bounds__(256) void cvt8_kernel(const float* __restrict__ in,
                                                   bf16_t* __restrict__ out, int n8) {
    int i = blockIdx.x * blockDim.x + threadIdx.x;
    if (i >= n8) return;
    const float4 a = *(const float4*)(in + (size_t)i * 8);
    const float4 b = *(const float4*)(in + (size_t)i * 8 + 4);
    bf16x8 r;
    r[0] = (bf16_t)a.x; r[1] = (bf16_t)a.y; r[2] = (bf16_t)a.z; r[3] = (bf16_t)a.w;
    r[4] = (bf16_t)b.x; r[5] = (bf16_t)b.y; r[6] = (bf16_t)b.z; r[7] = (bf16_t)b.w;
    *(bf16x8*)(out + (size_t)i * 8) = r;
}

// ---------------- fp32 KxN -> bf16 NxK transpose-convert ----------------
__global__ __launch_bounds__(256) void cvtT_kernel(const float* __restrict__ in,
                                                   bf16_t* __restrict__ out, int K, int N) {
    __shared__ float t[64][65];
    const int n0 = blockIdx.x * 64, k0 = blockIdx.y * 64;
    const int tid = threadIdx.x, c = tid & 63, r4 = tid >> 6;
#pragma unroll
    for (int rr = 0; rr < 64; rr += 4)
        t[rr + r4][c] = in[(size_t)(k0 + rr + r4) * N + n0 + c];
    __syncthreads();
#pragma unroll
    for (int rr = 0; rr < 64; rr += 4) {
        int nn = rr + r4;
        out[(size_t)(n0 + nn) * K + k0 + c] = (bf16_t)t[c][nn];
    }
}

// ---------------- bf16 GEMM: C[M][N] = A[M][K] * Bt[N][K]^T + bias ----------------
template <typename OUTT>
__global__ __launch_bounds__(256) void gemm_bt(const bf16_t* __restrict__ A,
                                               const bf16_t* __restrict__ Bt,
                                               const float* __restrict__ bias,
                                               OUTT* __restrict__ C,
                                               int M, int N, int K) {
    __shared__ __align__(16) bf16_t As[128 * 32];
    __shared__ __align__(16) bf16_t Bs[128 * 32];
    const int tid = threadIdx.x;
    const int wid = tid >> 6, lane = tid & 63;
    const int wr = wid >> 1, wc = wid & 1;
    const int lr = lane & 15, lg = lane >> 4;
    const int m0 = blockIdx.x * 128, n0 = blockIdx.y * 128;

    // staging: 8 chunks of 1024B each for A and for B; wave handles 2 + 2
    const bf16_t* ga0 = A + (size_t)(m0 + wid * 32 + (lane >> 2)) * K + (lane & 3) * 8;
    const bf16_t* ga1 = ga0 + (size_t)16 * K;
    const bf16_t* gb0 = Bt + (size_t)(n0 + wid * 32 + (lane >> 2)) * K + (lane & 3) * 8;
    const bf16_t* gb1 = gb0 + (size_t)16 * K;
    bf16_t* la0 = &As[wid * 1024];
    bf16_t* la1 = &As[wid * 1024 + 512];
    bf16_t* lb0 = &Bs[wid * 1024];
    bf16_t* lb1 = &Bs[wid * 1024 + 512];

    f32x4 zero4 = {0.f, 0.f, 0.f, 0.f};
    f32x4 acc[4][4];
#pragma unroll
    for (int m = 0; m < 4; ++m)
#pragma unroll
        for (int n = 0; n < 4; ++n) acc[m][n] = zero4;

    const int aoff = (wr * 64 + lr) * 32 + lg * 8;
    const int boff = (wc * 64 + lr) * 32 + lg * 8;

    for (int kt = 0; kt < K; kt += 32) {
        gload16(ga0 + kt, la0);
        gload16(ga1 + kt, la1);
        gload16(gb0 + kt, lb0);
        gload16(gb1 + kt, lb1);
        __syncthreads();
        bf16x8 af[4], bfr[4];
#pragma unroll
        for (int m = 0; m < 4; ++m) af[m] = *(const bf16x8*)&As[aoff + m * 512];
#pragma unroll
        for (int n = 0; n < 4; ++n) bfr[n] = *(const bf16x8*)&Bs[boff + n * 512];
#pragma unroll
        for (int m = 0; m < 4; ++m)
#pragma unroll
            for (int n = 0; n < 4; ++n)
                acc[m][n] = __builtin_amdgcn_mfma_f32_16x16x32_bf16(af[m], bfr[n], acc[m][n], 0, 0, 0);
        __syncthreads();
    }

#pragma unroll
    for (int n = 0; n < 4; ++n) {
        int col = n0 + wc * 64 + n * 16 + lr;
        float bs = bias[col];
#pragma unroll
        for (int m = 0; m < 4; ++m) {
            int row = m0 + wr * 64 + m * 16 + lg * 4;
#pragma unroll
            for (int i = 0; i < 4; ++i) {
                float v = acc[m][n][i] + bs;
                C[(size_t)(row + i) * N + col] = (OUTT)v;
            }
        }
    }
}

// ---------------- MRoPE + split/transpose q,k,v ----------------
__global__ __launch_bounds__(256) void rope_kernel(const bf16_t* __restrict__ qkv,
                                                   bf16_t* __restrict__ qT,
                                                   bf16_t* __restrict__ kT,
                                                   bf16_t* __restrict__ vN,
                                                   const int* __restrict__ Hp,
                                                   const int* __restrict__ Wp) {
    const int bn = blockIdx.x;
    const int b = bn >> 11, n = bn & 2047;
    __shared__ float cs[64], sn[64];
    const int tid = threadIdx.x;
    if (tid < 64) {
        int Hh = *Hp, Ww = *Wp;
        int t = n / (Hh * Ww);
        int rem = n % (Hh * Ww);
        int h = rem / Ww, w = rem % Ww;
        float pos = (tid < 16) ? (float)t : (tid < 40 ? (float)h : (float)w);
        // inv_freq = theta^(-j/64), ln(10000) = 9.210340371976184
        float inv = expf(-(float)tid * (9.210340371976184f / 64.f));
        float ang = pos * inv;
        cs[tid] = cosf(ang);
        sn[tid] = sinf(ang);
    }
    __syncthreads();
    const bf16_t* base = qkv + (size_t)bn * QKVCOLS;
    const float qscale = 0.08838834764831845f;  // 1/sqrt(128)
    for (int p = tid; p < 1024; p += 256) {
        int hh = p >> 6, j = p & 63;
        float c = cs[j], s = sn[j];
        size_t o = ((size_t)(b * NHEADS + hh) * NTOK + n) * HD;
        float x1 = (float)base[hh * 128 + j];
        float x2 = (float)base[hh * 128 + j + 64];
        qT[o + j] = (bf16_t)((x1 * c - x2 * s) * qscale);
        qT[o + j + 64] = (bf16_t)((x2 * c + x1 * s) * qscale);
        x1 = (float)base[2048 + hh * 128 + j];
        x2 = (float)base[2048 + hh * 128 + j + 64];
        kT[o + j] = (bf16_t)(x1 * c - x2 * s);
        kT[o + j + 64] = (bf16_t)(x2 * c + x1 * s);
        vN[o + j] = base[4096 + hh * 128 + j];
        vN[o + j + 64] = base[4096 + hh * 128 + j + 64];
    }
}

// ---------------- v: [bh][n][d] -> [bh][d][n] ----------------
__global__ __launch_bounds__(256) void transpose_v(const bf16_t* __restrict__ vN,
                                                   bf16_t* __restrict__ vT) {
    __shared__ bf16_t t[64][65];
    const int bh = blockIdx.z;
    const int d0 = blockIdx.x * 64, n0 = blockIdx.y * 64;
    const bf16_t* in = vN + (size_t)bh * NTOK * HD;
    bf16_t* out = vT + (size_t)bh * NTOK * HD;
    const int tid = threadIdx.x, c = tid & 63, r4 = tid >> 6;
#pragma unroll
    for (int rr = 0; rr < 64; rr += 4)
        t[rr + r4][c] = in[(size_t)(n0 + rr + r4) * HD + d0 + c];
    __syncthreads();
#pragma unroll
    for (int rr = 0; rr < 64; rr += 4) {
        int dd = rr + r4;
        out[(size_t)(d0 + dd) * NTOK + n0 + c] = t[c][dd];
    }
}

// ---------------- flash attention, 64 q-rows/block, 4 waves ----------------
__global__ __launch_bounds__(256) void attn_kernel(const bf16_t* __restrict__ qT,
                                                   const bf16_t* __restrict__ kT,
                                                   const bf16_t* __restrict__ vT,
                                                   bf16_t* __restrict__ outp) {
    const int bh = blockIdx.y;
    const int q0 = blockIdx.x * 64;
    const int tid = threadIdx.x, wid = tid >> 6, lane = tid & 63;
    const int lr = lane & 15, lg = lane >> 4;
    const bf16_t* Q = qT + (size_t)bh * NTOK * HD;
    const bf16_t* Kp = kT + (size_t)bh * NTOK * HD;
    const bf16_t* Vp = vT + (size_t)bh * NTOK * HD;  // [d][n]

    __shared__ __align__(16) bf16_t Ks[64][136];   // +8 pad
    __shared__ __align__(16) bf16_t Vs[128][72];   // +8 pad
    __shared__ __align__(16) bf16_t Ps[4][16][72]; // per-wave

    bf16x8 qf[4];
    {
        const bf16_t* qr = Q + (size_t)(q0 + wid * 16 + lr) * HD + lg * 8;
#pragma unroll
        for (int ks = 0; ks < 4; ++ks) qf[ks] = *(const bf16x8*)(qr + ks * 32);
    }
    f32x4 zero4 = {0.f, 0.f, 0.f, 0.f};
    f32x4 oa[8];
#pragma unroll
    for (int df = 0; df < 8; ++df) oa[df] = zero4;
    float m_run[4], l_run[4];
#pragma unroll
    for (int i = 0; i < 4; ++i) { m_run[i] = -1e30f; l_run[i] = 0.f; }

    for (int kt = 0; kt < NTOK; kt += 64) {
        // stage K tile [64][128] and V^T tile [128][64] via regs into padded LDS
#pragma unroll
        for (int it = 0; it < 4; ++it) {
            int ch = tid + 256 * it;
            int r = ch >> 4, c = (ch & 15) * 8;
            *(bf16x8*)&Ks[r][c] = *(const bf16x8*)(Kp + (size_t)(kt + r) * HD + c);
            int r2 = ch >> 3, c2 = (ch & 7) * 8;
            *(bf16x8*)&Vs[r2][c2] = *(const bf16x8*)(Vp + (size_t)r2 * NTOK + kt + c2);
        }
        __syncthreads();
        // S = Q K^T  (wave's 16 q-rows x 64 kv)
        f32x4 s[4];
#pragma unroll
        for (int nf = 0; nf < 4; ++nf) s[nf] = zero4;
#pragma unroll
        for (int nf = 0; nf < 4; ++nf)
#pragma unroll
            for (int ks = 0; ks < 4; ++ks) {
                bf16x8 kf = *(const bf16x8*)&Ks[nf * 16 + lr][ks * 32 + lg * 8];
                s[nf] = __builtin_amdgcn_mfma_f32_16x16x32_bf16(qf[ks], kf, s[nf], 0, 0, 0);
            }
        // online softmax; row = lg*4 + i
        float p[4][4];
#pragma unroll
        for (int i = 0; i < 4; ++i) {
            float mx = fmaxf(fmaxf(s[0][i], s[1][i]), fmaxf(s[2][i], s[3][i]));
#pragma unroll
            for (int d = 1; d < 16; d <<= 1) mx = fmaxf(mx, __shfl_xor(mx, d, 64));
            float mo = m_run[i];
            float mn = fmaxf(mo, mx);
            float resc = __expf(mo - mn);
            m_run[i] = mn;
            float rs = 0.f;
#pragma unroll
            for (int nf = 0; nf < 4; ++nf) {
                float e = __expf(s[nf][i] - mn);
                p[nf][i] = e;
                rs += e;
            }
#pragma unroll
            for (int d = 1; d < 16; d <<= 1) rs += __shfl_xor(rs, d, 64);
            l_run[i] = l_run[i] * resc + rs;
#pragma unroll
            for (int df = 0; df < 8; ++df) oa[df][i] *= resc;
        }
        // P -> LDS (per-wave, D-layout -> A-layout transpose)
#pragma unroll
        for (int nf = 0; nf < 4; ++nf)
#pragma unroll
            for (int i = 0; i < 4; ++i)
                Ps[wid][lg * 4 + i][nf * 16 + lr] = (bf16_t)p[nf][i];
        // PV
        bf16x8 pf0 = *(const bf16x8*)&Ps[wid][lr][lg * 8];
        bf16x8 pf1 = *(const bf16x8*)&Ps[wid][lr][32 + lg * 8];
#pragma unroll
        for (int df = 0; df < 8; ++df) {
            bf16x8 v0 = *(const bf16x8*)&Vs[df * 16 + lr][lg * 8];
            bf16x8 v1 = *(const bf16x8*)&Vs[df * 16 + lr][32 + lg * 8];
            oa[df] = __builtin_amdgcn_mfma_f32_16x16x32_bf16(pf0, v0, oa[df], 0, 0, 0);
            oa[df] = __builtin_amdgcn_mfma_f32_16x16x32_bf16(pf1, v1, oa[df], 0, 0, 0);
        }
        __syncthreads();
    }
    // epilogue: out[b*N + q][h*128 + d]
    const int b = bh >> 4, h = bh & 15;
#pragma unroll
    for (int i = 0; i < 4; ++i) {
        float inv = 1.0f / l_run[i];
        size_t row = (size_t)(b * NTOK + q0 + wid * 16 + lg * 4 + i);
        bf16_t* orow = outp + row * HIDDEN + h * HD;
#pragma unroll
        for (int df = 0; df < 8; ++df)
            orow[df * 16 + lr] = (bf16_t)(oa[df][i] * inv);
    }
}

extern "C" void kernel_launch(void* const* d_in, const int* in_sizes, int n_in,
                              void* d_out, int out_size, void* d_ws, size_t ws_size,
                              hipStream_t stream) {
    const float* x = (const float*)d_in[0];
    const float* w_qkv = (const float*)d_in[1];
    const float* b_qkv = (const float*)d_in[2];
    const float* w_proj = (const float*)d_in[3];
    const float* b_proj = (const float*)d_in[4];
    const int* Hp = (const int*)d_in[6];
    const int* Wp = (const int*)d_in[7];
    float* out = (float*)d_out;

    char* ws = (char*)d_ws;
    bf16_t* xb = (bf16_t*)(ws + 0);                       // 16 MiB  [4096][2048]
    bf16_t* wqkvT = (bf16_t*)(ws + 16777216);             // 24 MiB  [6144][2048]
    bf16_t* wprojT = (bf16_t*)(ws + 41943040);            // 8 MiB   [2048][2048]
    bf16_t* qkv = (bf16_t*)(ws + 50331648);               // 48 MiB  [4096][6144]
    bf16_t* qTb = (bf16_t*)(ws + 100663296);              // 16 MiB  [32][2048][128]
    bf16_t* kTb = (bf16_t*)(ws + 117440512);              // 16 MiB
    bf16_t* vN = (bf16_t*)(ws + 0);                       // reuse xb region after gemm1
    bf16_t* vT = (bf16_t*)(ws + 16777216);                // reuse wqkvT region
    bf16_t* attno = (bf16_t*)(ws + 50331648);             // reuse qkv region after rope

    cvt8_kernel<<<4096, 256, 0, stream>>>(x, xb, 1048576);
    cvtT_kernel<<<dim3(96, 32), 256, 0, stream>>>(w_qkv, wqkvT, 2048, 6144);
    cvtT_kernel<<<dim3(32, 32), 256, 0, stream>>>(w_proj, wprojT, 2048, 2048);
    gemm_bt<bf16_t><<<dim3(32, 48), 256, 0, stream>>>(xb, wqkvT, b_qkv, qkv, MROWS, QKVCOLS, HIDDEN);
    rope_kernel<<<4096, 256, 0, stream>>>(qkv, qTb, kTb, vN, Hp, Wp);
    transpose_v<<<dim3(2, 32, 32), 256, 0, stream>>>(vN, vT);
    attn_kernel<<<dim3(32, 32), 256, 0, stream>>>(qTb, kTb, vT, attno);
    gemm_bt<float><<<dim3(32, 16), 256, 0, stream>>>(attno, wprojT, b_proj, out, MROWS, HIDDEN, HIDDEN);
}

// Round 2
// 324.136 us; speedup vs baseline: 1.5555x; 1.5555x over previous
//
#include <hip/hip_runtime.h>
#include <hip/hip_bf16.h>

typedef __bf16 bf16_t;
typedef __bf16 bf16x8 __attribute__((ext_vector_type(8)));
typedef __bf16 bf16x4 __attribute__((ext_vector_type(4)));
typedef float f32x4 __attribute__((ext_vector_type(4)));
typedef float f32x16 __attribute__((ext_vector_type(16)));

#define HIDDEN 2048
#define NHEADS 16
#define HD 128
#define NTOK 2048
#define BATCH 2
#define MROWS (BATCH*NTOK)
#define QKVCOLS (3*HIDDEN)

__device__ __forceinline__ void gload16(const void* g, void* l) {
    __builtin_amdgcn_global_load_lds(
        (const __attribute__((address_space(1))) void*)g,
        (__attribute__((address_space(3))) void*)l,
        16, 0, 0);
}

__device__ __forceinline__ unsigned int pack2bf(float lo, float hi2) {
    union { bf16_t h[2]; unsigned int u; } t;
    t.h[0] = (bf16_t)lo; t.h[1] = (bf16_t)hi2;
    return t.u;
}

// ---------------- fp32 -> bf16 elementwise (x) ----------------
__global__ __launch_bounds__(256) void cvt8_kernel(const float* __restrict__ in,
                                                   bf16_t* __restrict__ out, int n8) {
    int i = blockIdx.x * blockDim.x + threadIdx.x;
    if (i >= n8) return;
    const float4 a = *(const float4*)(in + (size_t)i * 8);
    const float4 b = *(const float4*)(in + (size_t)i * 8 + 4);
    bf16x8 r;
    r[0] = (bf16_t)a.x; r[1] = (bf16_t)a.y; r[2] = (bf16_t)a.z; r[3] = (bf16_t)a.w;
    r[4] = (bf16_t)b.x; r[5] = (bf16_t)b.y; r[6] = (bf16_t)b.z; r[7] = (bf16_t)b.w;
    *(bf16x8*)(out + (size_t)i * 8) = r;
}

// ---------------- fp32 KxN -> bf16 NxK transpose-convert ----------------
__global__ __launch_bounds__(256) void cvtT_kernel(const float* __restrict__ in,
                                                   bf16_t* __restrict__ out, int K, int N) {
    __shared__ float t[64][65];
    const int n0 = blockIdx.x * 64, k0 = blockIdx.y * 64;
    const int tid = threadIdx.x, c = tid & 63, r4 = tid >> 6;
#pragma unroll
    for (int rr = 0; rr < 64; rr += 4)
        t[rr + r4][c] = in[(size_t)(k0 + rr + r4) * N + n0 + c];
    __syncthreads();
#pragma unroll
    for (int rr = 0; rr < 64; rr += 4) {
        int nn = rr + r4;
        out[(size_t)(n0 + nn) * K + k0 + c] = (bf16_t)t[c][nn];
    }
}

// ---------------- bf16 GEMM: C[M][N] = A[M][K] * Bt[N][K]^T + bias ----------------
template <typename OUTT>
__global__ __launch_bounds__(256) void gemm_bt(const bf16_t* __restrict__ A,
                                               const bf16_t* __restrict__ Bt,
                                               const float* __restrict__ bias,
                                               OUTT* __restrict__ C,
                                               int M, int N, int K) {
    __shared__ __align__(16) bf16_t As[128 * 32];
    __shared__ __align__(16) bf16_t Bs[128 * 32];
    const int tid = threadIdx.x;
    const int wid = tid >> 6, lane = tid & 63;
    const int wr = wid >> 1, wc = wid & 1;
    const int lr = lane & 15, lg = lane >> 4;
    const int m0 = blockIdx.x * 128, n0 = blockIdx.y * 128;

    const bf16_t* ga0 = A + (size_t)(m0 + wid * 32 + (lane >> 2)) * K + (lane & 3) * 8;
    const bf16_t* ga1 = ga0 + (size_t)16 * K;
    const bf16_t* gb0 = Bt + (size_t)(n0 + wid * 32 + (lane >> 2)) * K + (lane & 3) * 8;
    const bf16_t* gb1 = gb0 + (size_t)16 * K;
    bf16_t* la0 = &As[wid * 1024];
    bf16_t* la1 = &As[wid * 1024 + 512];
    bf16_t* lb0 = &Bs[wid * 1024];
    bf16_t* lb1 = &Bs[wid * 1024 + 512];

    f32x4 zero4 = {0.f, 0.f, 0.f, 0.f};
    f32x4 acc[4][4];
#pragma unroll
    for (int m = 0; m < 4; ++m)
#pragma unroll
        for (int n = 0; n < 4; ++n) acc[m][n] = zero4;

    const int aoff = (wr * 64 + lr) * 32 + lg * 8;
    const int boff = (wc * 64 + lr) * 32 + lg * 8;

    for (int kt = 0; kt < K; kt += 32) {
        gload16(ga0 + kt, la0);
        gload16(ga1 + kt, la1);
        gload16(gb0 + kt, lb0);
        gload16(gb1 + kt, lb1);
        __syncthreads();
        bf16x8 af[4], bfr[4];
#pragma unroll
        for (int m = 0; m < 4; ++m) af[m] = *(const bf16x8*)&As[aoff + m * 512];
#pragma unroll
        for (int n = 0; n < 4; ++n) bfr[n] = *(const bf16x8*)&Bs[boff + n * 512];
#pragma unroll
        for (int m = 0; m < 4; ++m)
#pragma unroll
            for (int n = 0; n < 4; ++n)
                acc[m][n] = __builtin_amdgcn_mfma_f32_16x16x32_bf16(af[m], bfr[n], acc[m][n], 0, 0, 0);
        __syncthreads();
    }

#pragma unroll
    for (int n = 0; n < 4; ++n) {
        int col = n0 + wc * 64 + n * 16 + lr;
        float bs = bias[col];
#pragma unroll
        for (int m = 0; m < 4; ++m) {
            int row = m0 + wr * 64 + m * 16 + lg * 4;
#pragma unroll
            for (int i = 0; i < 4; ++i) {
                float v = acc[m][n][i] + bs;
                C[(size_t)(row + i) * N + col] = (OUTT)v;
            }
        }
    }
}

// ---------------- MRoPE + split/transpose q,k,v ----------------
__global__ __launch_bounds__(256) void rope_kernel(const bf16_t* __restrict__ qkv,
                                                   bf16_t* __restrict__ qT,
                                                   bf16_t* __restrict__ kT,
                                                   bf16_t* __restrict__ vN,
                                                   const int* __restrict__ Hp,
                                                   const int* __restrict__ Wp) {
    const int bn = blockIdx.x;
    const int b = bn >> 11, n = bn & 2047;
    __shared__ float cs[64], sn[64];
    const int tid = threadIdx.x;
    if (tid < 64) {
        int Hh = *Hp, Ww = *Wp;
        int t = n / (Hh * Ww);
        int rem = n % (Hh * Ww);
        int h = rem / Ww, w = rem % Ww;
        float pos = (tid < 16) ? (float)t : (tid < 40 ? (float)h : (float)w);
        float inv = expf(-(float)tid * (9.210340371976184f / 64.f));
        float ang = pos * inv;
        cs[tid] = cosf(ang);
        sn[tid] = sinf(ang);
    }
    __syncthreads();
    const bf16_t* base = qkv + (size_t)bn * QKVCOLS;
    const float qscale = 0.08838834764831845f;  // 1/sqrt(128)
    for (int p = tid; p < 1024; p += 256) {
        int hh = p >> 6, j = p & 63;
        float c = cs[j], s = sn[j];
        size_t o = ((size_t)(b * NHEADS + hh) * NTOK + n) * HD;
        float x1 = (float)base[hh * 128 + j];
        float x2 = (float)base[hh * 128 + j + 64];
        qT[o + j] = (bf16_t)((x1 * c - x2 * s) * qscale);
        qT[o + j + 64] = (bf16_t)((x2 * c + x1 * s) * qscale);
        x1 = (float)base[2048 + hh * 128 + j];
        x2 = (float)base[2048 + hh * 128 + j + 64];
        kT[o + j] = (bf16_t)(x1 * c - x2 * s);
        kT[o + j + 64] = (bf16_t)(x2 * c + x1 * s);
        vN[o + j] = base[4096 + hh * 128 + j];
        vN[o + j + 64] = base[4096 + hh * 128 + j + 64];
    }
}

// ---------------- v: [bh][n][d] -> [bh][d][n] ----------------
__global__ __launch_bounds__(256) void transpose_v(const bf16_t* __restrict__ vN,
                                                   bf16_t* __restrict__ vT) {
    __shared__ bf16_t t[64][65];
    const int bh = blockIdx.z;
    const int d0 = blockIdx.x * 64, n0 = blockIdx.y * 64;
    const bf16_t* in = vN + (size_t)bh * NTOK * HD;
    bf16_t* out = vT + (size_t)bh * NTOK * HD;
    const int tid = threadIdx.x, c = tid & 63, r4 = tid >> 6;
#pragma unroll
    for (int rr = 0; rr < 64; rr += 4)
        t[rr + r4][c] = in[(size_t)(n0 + rr + r4) * HD + d0 + c];
    __syncthreads();
#pragma unroll
    for (int rr = 0; rr < 64; rr += 4) {
        int dd = rr + r4;
        out[(size_t)(d0 + dd) * NTOK + n0 + c] = t[c][dd];
    }
}

// ---------------- flash attention v2: 4 waves x 32 q-rows, 32x32 MFMA ----------------
// Swapped QK^T (mfma(K,Q)) -> lane-local softmax rows; in-register P; swizzled
// K/V LDS staged via global_load_lds with pre-swizzled source; double-buffered.
__global__ __launch_bounds__(256, 2) void attn_kernel(const bf16_t* __restrict__ qT,
                                                      const bf16_t* __restrict__ kT,
                                                      const bf16_t* __restrict__ vT,
                                                      bf16_t* __restrict__ outp) {
    __shared__ __align__(16) char lds[2][32768];  // per buf: K tile 16KB | V tile 16KB
    const int B = blockIdx.x;
    const int xcd = B & 7, jj = B >> 3;
    const int bh = xcd * 4 + (jj >> 4);
    const int q0 = (jj & 15) * 128;
    const int tid = threadIdx.x, wid = tid >> 6, lane = tid & 63;
    const int ql = lane & 31, hi = lane >> 5;

    const bf16_t* Q = qT + (size_t)bh * NTOK * HD;
    const char* Kb = (const char*)(kT + (size_t)bh * NTOK * HD);
    const char* Vb = (const char*)(vT + (size_t)bh * NTOK * HD);

    // Q fragments: B-operand, col=ql, k = kc*16 + hi*8 + j
    bf16x8 qf[8];
    {
        const bf16_t* qrow = Q + (size_t)(q0 + wid * 32 + ql) * HD + hi * 8;
#pragma unroll
        for (int kc = 0; kc < 8; ++kc) qf[kc] = *(const bf16x8*)(qrow + kc * 16);
    }
    f32x16 oa[4];
#pragma unroll
    for (int df = 0; df < 4; ++df)
#pragma unroll
        for (int r = 0; r < 16; ++r) oa[df][r] = 0.f;
    float m_run = -1e30f, l_run = 0.f;

    auto stage = [&](int t, int buf) {
        // K tile [64 kv][128 d], swizzled: content[a] = K[a^((row&7)<<4)]
#pragma unroll
        for (int i = 0; i < 4; ++i) {
            int a = wid * 4096 + i * 1024 + lane * 16;
            int row = a >> 8;
            int col = (a & 255) ^ ((row & 7) << 4);
            gload16(Kb + (size_t)(t * 64 + row) * 256 + col,
                    (char*)lds[buf] + wid * 4096 + i * 1024);
        }
        // V^T tile [128 d][64 kv], swizzled
#pragma unroll
        for (int i = 0; i < 4; ++i) {
            int a = wid * 4096 + i * 1024 + lane * 16;
            int row = a >> 7;
            int col = (a & 127) ^ ((row & 7) << 4);
            gload16(Vb + (size_t)row * (NTOK * 2) + t * 128 + col,
                    (char*)lds[buf] + 16384 + wid * 4096 + i * 1024);
        }
    };
    stage(0, 0);
    __syncthreads();

    for (int t = 0; t < NTOK / 64; ++t) {
        if (t < NTOK / 64 - 1) stage(t + 1, (t + 1) & 1);
        const char* Kl = lds[t & 1];
        const char* Vl = Kl + 16384;

        // ---- S^T = K · Q^T : s[nb][reg] = S[kv = nb*32 + (reg&3)+8*(reg>>2)+4*hi][q=ql]
        f32x16 s[2];
#pragma unroll
        for (int nb = 0; nb < 2; ++nb) {
#pragma unroll
            for (int r = 0; r < 16; ++r) s[nb][r] = 0.f;
            int row = nb * 32 + ql;
            const char* krow = Kl + row * 256;
            int sw = (row & 7) << 4;
#pragma unroll
            for (int kc = 0; kc < 8; ++kc) {
                bf16x8 kf = *(const bf16x8*)(krow + ((kc * 32 + hi * 16) ^ sw));
                s[nb] = __builtin_amdgcn_mfma_f32_32x32x16_bf16(kf, qf[kc], s[nb], 0, 0, 0);
            }
        }

        // ---- online softmax (row q=ql is split between this lane and lane^32)
        float mx = s[0][0];
#pragma unroll
        for (int r = 1; r < 16; ++r) mx = fmaxf(mx, s[0][r]);
#pragma unroll
        for (int r = 0; r < 16; ++r) mx = fmaxf(mx, s[1][r]);
        mx = fmaxf(mx, __shfl_xor(mx, 32));
        if (__any(mx - m_run > 8.f)) {  // defer-max: rescale only on real growth
            float mn = fmaxf(m_run, mx);
            float resc = __expf(m_run - mn);
            l_run *= resc;
#pragma unroll
            for (int df = 0; df < 4; ++df) oa[df] *= resc;
            m_run = mn;
        }
        float rs = 0.f;
#pragma unroll
        for (int nb = 0; nb < 2; ++nb)
#pragma unroll
            for (int r = 0; r < 16; ++r) {
                float e = __expf(s[nb][r] - m_run);
                s[nb][r] = e;
                rs += e;
            }
        rs += __shfl_xor(rs, 32);
        l_run += rs;

        // ---- pack P to bf16 pairs: pk[nb][m] covers kv pair (r=2m, 2m+1)
        unsigned int pk[2][8];
#pragma unroll
        for (int nb = 0; nb < 2; ++nb)
#pragma unroll
            for (int m = 0; m < 8; ++m) pk[nb][m] = pack2bf(s[nb][2 * m], s[nb][2 * m + 1]);

        // ---- PV: O^T += V^T · P^T
#pragma unroll
        for (int kc2 = 0; kc2 < 4; ++kc2) {
            const int nb = kc2 >> 1, c1 = kc2 & 1;
            union { unsigned int u[4]; bf16x8 v; } pb;
#pragma unroll
            for (int j = 0; j < 4; ++j) {
                const int bsel = (j & 1) + 4 * c1;
                unsigned int vlo = pk[nb][bsel];      // data slot for hi_t=0
                unsigned int vhi = pk[nb][bsel + 2];  // data slot for hi_t=1
                unsigned int mine = hi ? vhi : vlo;
                unsigned int yours = hi ? vlo : vhi;
                unsigned int x = (unsigned int)__shfl_xor((int)yours, 32);
                pb.u[j] = (hi == (j >> 1)) ? mine : x;
            }
#pragma unroll
            for (int df = 0; df < 4; ++df) {
                int row = df * 32 + ql;
                bf16x8 va = *(const bf16x8*)(Vl + row * 128 + ((kc2 * 32 + hi * 16) ^ ((row & 7) << 4)));
                oa[df] = __builtin_amdgcn_mfma_f32_32x32x16_bf16(va, pb.v, oa[df], 0, 0, 0);
            }
        }
        __syncthreads();
    }

    // ---- epilogue: O^T (lane-held) -> per-wave LDS [32 q][136 d] -> coalesced store
    float inv = 1.f / l_run;
    bf16_t* Ot = (bf16_t*)((char*)lds + wid * 8704);
#pragma unroll
    for (int df = 0; df < 4; ++df)
#pragma unroll
        for (int rg = 0; rg < 4; ++rg) {
            bf16x4 w;
#pragma unroll
            for (int i = 0; i < 4; ++i) w[i] = (bf16_t)(oa[df][rg * 4 + i] * inv);
            int d0 = df * 32 + rg * 8 + hi * 4;
            *(bf16x4*)&Ot[ql * 136 + d0] = w;
        }
    __builtin_amdgcn_s_waitcnt(0);  // lgkmcnt(0)+vmcnt(0): ds_writes visible (same wave)
    const int qloc = lane >> 1, half = lane & 1;
    const int b = bh >> 4, h = bh & 15;
    bf16_t* orow = outp + (size_t)(b * NTOK + q0 + wid * 32 + qloc) * HIDDEN + h * HD + half * 64;
    const bf16_t* src = Ot + qloc * 136 + half * 64;
#pragma unroll
    for (int c = 0; c < 8; ++c)
        *(bf16x8*)(orow + c * 8) = *(const bf16x8*)(src + c * 8);
}

extern "C" void kernel_launch(void* const* d_in, const int* in_sizes, int n_in,
                              void* d_out, int out_size, void* d_ws, size_t ws_size,
                              hipStream_t stream) {
    const float* x = (const float*)d_in[0];
    const float* w_qkv = (const float*)d_in[1];
    const float* b_qkv = (const float*)d_in[2];
    const float* w_proj = (const float*)d_in[3];
    const float* b_proj = (const float*)d_in[4];
    const int* Hp = (const int*)d_in[6];
    const int* Wp = (const int*)d_in[7];
    float* out = (float*)d_out;

    char* ws = (char*)d_ws;
    bf16_t* xb = (bf16_t*)(ws + 0);                       // 16 MiB  [4096][2048]
    bf16_t* wqkvT = (bf16_t*)(ws + 16777216);             // 24 MiB  [6144][2048]
    bf16_t* wprojT = (bf16_t*)(ws + 41943040);            // 8 MiB   [2048][2048]
    bf16_t* qkv = (bf16_t*)(ws + 50331648);               // 48 MiB  [4096][6144]
    bf16_t* qTb = (bf16_t*)(ws + 100663296);              // 16 MiB  [32][2048][128]
    bf16_t* kTb = (bf16_t*)(ws + 117440512);              // 16 MiB
    bf16_t* vN = (bf16_t*)(ws + 0);                       // reuse xb region after gemm1
    bf16_t* vT = (bf16_t*)(ws + 16777216);                // reuse wqkvT region
    bf16_t* attno = (bf16_t*)(ws + 50331648);             // reuse qkv region after rope

    cvt8_kernel<<<4096, 256, 0, stream>>>(x, xb, 1048576);
    cvtT_kernel<<<dim3(96, 32), 256, 0, stream>>>(w_qkv, wqkvT, 2048, 6144);
    cvtT_kernel<<<dim3(32, 32), 256, 0, stream>>>(w_proj, wprojT, 2048, 2048);
    gemm_bt<bf16_t><<<dim3(32, 48), 256, 0, stream>>>(xb, wqkvT, b_qkv, qkv, MROWS, QKVCOLS, HIDDEN);
    rope_kernel<<<4096, 256, 0, stream>>>(qkv, qTb, kTb, vN, Hp, Wp);
    transpose_v<<<dim3(2, 32, 32), 256, 0, stream>>>(vN, vT);
    attn_kernel<<<512, 256, 0, stream>>>(qTb, kTb, vT, attno);
    gemm_bt<float><<<dim3(32, 16), 256, 0, stream>>>(attno, wprojT, b_proj, out, MROWS, HIDDEN, HIDDEN);
}

// Round 3
// 294.149 us; speedup vs baseline: 1.7141x; 1.1019x over previous
//
#include <hip/hip_runtime.h>
#include <hip/hip_bf16.h>

typedef __bf16 bf16_t;
typedef __bf16 bf16x8 __attribute__((ext_vector_type(8)));
typedef __bf16 bf16x4 __attribute__((ext_vector_type(4)));
typedef float f32x4 __attribute__((ext_vector_type(4)));
typedef float f32x16 __attribute__((ext_vector_type(16)));

#define HIDDEN 2048
#define NHEADS 16
#define HD 128
#define NTOK 2048
#define BATCH 2
#define MROWS (BATCH*NTOK)
#define QKVCOLS (3*HIDDEN)

__device__ __forceinline__ void gload16(const void* g, void* l) {
    __builtin_amdgcn_global_load_lds(
        (const __attribute__((address_space(1))) void*)g,
        (__attribute__((address_space(3))) void*)l,
        16, 0, 0);
}

__device__ __forceinline__ unsigned int pack2bf(float lo, float hi2) {
    union { bf16_t h[2]; unsigned int u; } t;
    t.h[0] = (bf16_t)lo; t.h[1] = (bf16_t)hi2;
    return t.u;
}

// ---------------- fp32 -> bf16 elementwise (x) ----------------
__global__ __launch_bounds__(256) void cvt8_kernel(const float* __restrict__ in,
                                                   bf16_t* __restrict__ out, int n8) {
    int i = blockIdx.x * blockDim.x + threadIdx.x;
    if (i >= n8) return;
    const float4 a = *(const float4*)(in + (size_t)i * 8);
    const float4 b = *(const float4*)(in + (size_t)i * 8 + 4);
    bf16x8 r;
    r[0] = (bf16_t)a.x; r[1] = (bf16_t)a.y; r[2] = (bf16_t)a.z; r[3] = (bf16_t)a.w;
    r[4] = (bf16_t)b.x; r[5] = (bf16_t)b.y; r[6] = (bf16_t)b.z; r[7] = (bf16_t)b.w;
    *(bf16x8*)(out + (size_t)i * 8) = r;
}

// ---------------- fp32 KxN -> bf16 NxK transpose-convert ----------------
__global__ __launch_bounds__(256) void cvtT_kernel(const float* __restrict__ in,
                                                   bf16_t* __restrict__ out, int K, int N) {
    __shared__ float t[64][65];
    const int n0 = blockIdx.x * 64, k0 = blockIdx.y * 64;
    const int tid = threadIdx.x, c = tid & 63, r4 = tid >> 6;
#pragma unroll
    for (int rr = 0; rr < 64; rr += 4)
        t[rr + r4][c] = in[(size_t)(k0 + rr + r4) * N + n0 + c];
    __syncthreads();
#pragma unroll
    for (int rr = 0; rr < 64; rr += 4) {
        int nn = rr + r4;
        out[(size_t)(n0 + nn) * K + k0 + c] = (bf16_t)t[c][nn];
    }
}

// ---------------- deep-pipelined bf16 GEMM: C[M][N] = A * Bt^T + bias ----------------
// 128x256 tile, BK=32, 4 waves (each 128x64), 3 LDS buffers (stage depth 2),
// counted vmcnt(6) + raw s_barrier once per K-tile, T2 XOR-swizzle, T5 setprio.
template <typename OUTT>
__global__ __launch_bounds__(256, 2) void gemm_pipe(const bf16_t* __restrict__ A,
                                                    const bf16_t* __restrict__ Bt,
                                                    const float* __restrict__ bias,
                                                    OUTT* __restrict__ C,
                                                    int M, int N, int K) {
    __shared__ __align__(16) char lds[3][24576];  // per buf: A 8KB | B 16KB
    const int NKT = K >> 5;
    const int tid = threadIdx.x, wid = tid >> 6, lane = tid & 63;
    const int lr = lane & 15, lg = lane >> 4;
    // bijective XCD swizzle (grid % 8 == 0 for all our launches)
    const int nwg = gridDim.x, cpx = nwg >> 3;
    const int bid = blockIdx.x;
    const int swz = (bid & 7) * cpx + (bid >> 3);
    const int ntn = N >> 8;
    const int m0 = (swz / ntn) * 128, n0 = (swz % ntn) * 256;

    // staging: dest is linear (tid*16 + j*4096); source column pre-swizzled
    const int sc = (((tid & 3) ^ ((tid >> 3) & 3)) << 4);
    const int srow = tid >> 2;
    const char* pA0 = (const char*)A + ((size_t)(m0 + srow) * K) * 2 + sc;
    const char* pA1 = (const char*)A + ((size_t)(m0 + srow + 64) * K) * 2 + sc;
    const char* pB0 = (const char*)Bt + ((size_t)(n0 + srow) * K) * 2 + sc;
    const char* pB1 = (const char*)Bt + ((size_t)(n0 + srow + 64) * K) * 2 + sc;
    const char* pB2 = (const char*)Bt + ((size_t)(n0 + srow + 128) * K) * 2 + sc;
    const char* pB3 = (const char*)Bt + ((size_t)(n0 + srow + 192) * K) * 2 + sc;
    // fragment read offset: logical (row*64 + lg*16) with row-bit XOR folded in
    const int xoff = lr * 64 + ((lg ^ ((lr >> 1) & 3)) << 4);

    auto stage3a = [&](int kb, char* bp) {
        gload16(pA0 + kb, bp + tid * 16);
        gload16(pA1 + kb, bp + tid * 16 + 4096);
        gload16(pB0 + kb, bp + 8192 + tid * 16);
    };
    auto stage3b = [&](int kb, char* bp) {
        gload16(pB1 + kb, bp + 8192 + tid * 16 + 4096);
        gload16(pB2 + kb, bp + 8192 + tid * 16 + 8192);
        gload16(pB3 + kb, bp + 8192 + tid * 16 + 12288);
    };

    f32x4 acc[8][4];
#pragma unroll
    for (int m = 0; m < 8; ++m)
#pragma unroll
        for (int n = 0; n < 4; ++n) acc[m][n] = f32x4{0.f, 0.f, 0.f, 0.f};

    // prologue: tiles 0 and 1
    stage3a(0, lds[0]); stage3b(0, lds[0]);
    stage3a(64, lds[1]); stage3b(64, lds[1]);
    asm volatile("s_waitcnt vmcnt(6)" ::: "memory");
    __builtin_amdgcn_s_barrier();

    int cur = 0;
    for (int kt = 0; kt < NKT; ++kt) {
        const char* Al = lds[cur];
        const char* Bl = Al + 8192;
        int sb = cur + 2; if (sb >= 3) sb -= 3;
        char* sp = lds[sb];
        const bool st = (kt + 2) < NKT;
        const int kb = (kt + 2) << 6;

        bf16x8 bfr[4], afr[4];
#pragma unroll
        for (int n = 0; n < 4; ++n)
            bfr[n] = *(const bf16x8*)(Bl + wid * 4096 + n * 1024 + xoff);
#pragma unroll
        for (int m = 0; m < 4; ++m)
            afr[m] = *(const bf16x8*)(Al + m * 1024 + xoff);
        if (st) stage3a(kb, sp);
        __builtin_amdgcn_s_setprio(1);
#pragma unroll
        for (int m = 0; m < 4; ++m)
#pragma unroll
            for (int n = 0; n < 4; ++n)
                acc[m][n] = __builtin_amdgcn_mfma_f32_16x16x32_bf16(afr[m], bfr[n], acc[m][n], 0, 0, 0);
        __builtin_amdgcn_s_setprio(0);

#pragma unroll
        for (int m = 0; m < 4; ++m)
            afr[m] = *(const bf16x8*)(Al + (m + 4) * 1024 + xoff);
        if (st) stage3b(kb, sp);
        __builtin_amdgcn_s_setprio(1);
#pragma unroll
        for (int m = 0; m < 4; ++m)
#pragma unroll
            for (int n = 0; n < 4; ++n)
                acc[m + 4][n] = __builtin_amdgcn_mfma_f32_16x16x32_bf16(afr[m], bfr[n], acc[m + 4][n], 0, 0, 0);
        __builtin_amdgcn_s_setprio(0);

        if (kt < NKT - 1) {
            if (st) asm volatile("s_waitcnt vmcnt(6)" ::: "memory");
            else    asm volatile("s_waitcnt vmcnt(0)" ::: "memory");
            __builtin_amdgcn_s_barrier();
        }
        cur = cur + 1; if (cur >= 3) cur -= 3;
    }

    // epilogue
    float bvals[4];
#pragma unroll
    for (int n = 0; n < 4; ++n) bvals[n] = bias[n0 + wid * 64 + n * 16 + lr];
#pragma unroll
    for (int m = 0; m < 8; ++m) {
        const size_t row = (size_t)(m0 + m * 16 + lg * 4);
#pragma unroll
        for (int n = 0; n < 4; ++n) {
            const int col = n0 + wid * 64 + n * 16 + lr;
#pragma unroll
            for (int i = 0; i < 4; ++i)
                C[(row + i) * N + col] = (OUTT)(acc[m][n][i] + bvals[n]);
        }
    }
}

// ---------------- MRoPE + split/transpose q,k,v ----------------
__global__ __launch_bounds__(256) void rope_kernel(const bf16_t* __restrict__ qkv,
                                                   bf16_t* __restrict__ qT,
                                                   bf16_t* __restrict__ kT,
                                                   bf16_t* __restrict__ vN,
                                                   const int* __restrict__ Hp,
                                                   const int* __restrict__ Wp) {
    const int bn = blockIdx.x;
    const int b = bn >> 11, n = bn & 2047;
    __shared__ float cs[64], sn[64];
    const int tid = threadIdx.x;
    if (tid < 64) {
        int Hh = *Hp, Ww = *Wp;
        int t = n / (Hh * Ww);
        int rem = n % (Hh * Ww);
        int h = rem / Ww, w = rem % Ww;
        float pos = (tid < 16) ? (float)t : (tid < 40 ? (float)h : (float)w);
        float inv = expf(-(float)tid * (9.210340371976184f / 64.f));
        float ang = pos * inv;
        cs[tid] = cosf(ang);
        sn[tid] = sinf(ang);
    }
    __syncthreads();
    const bf16_t* base = qkv + (size_t)bn * QKVCOLS;
    const float qscale = 0.08838834764831845f;  // 1/sqrt(128)
    for (int p = tid; p < 1024; p += 256) {
        int hh = p >> 6, j = p & 63;
        float c = cs[j], s = sn[j];
        size_t o = ((size_t)(b * NHEADS + hh) * NTOK + n) * HD;
        float x1 = (float)base[hh * 128 + j];
        float x2 = (float)base[hh * 128 + j + 64];
        qT[o + j] = (bf16_t)((x1 * c - x2 * s) * qscale);
        qT[o + j + 64] = (bf16_t)((x2 * c + x1 * s) * qscale);
        x1 = (float)base[2048 + hh * 128 + j];
        x2 = (float)base[2048 + hh * 128 + j + 64];
        kT[o + j] = (bf16_t)(x1 * c - x2 * s);
        kT[o + j + 64] = (bf16_t)(x2 * c + x1 * s);
        vN[o + j] = base[4096 + hh * 128 + j];
        vN[o + j + 64] = base[4096 + hh * 128 + j + 64];
    }
}

// ---------------- v: [bh][n][d] -> [bh][d][n] ----------------
__global__ __launch_bounds__(256) void transpose_v(const bf16_t* __restrict__ vN,
                                                   bf16_t* __restrict__ vT) {
    __shared__ bf16_t t[64][65];
    const int bh = blockIdx.z;
    const int d0 = blockIdx.x * 64, n0 = blockIdx.y * 64;
    const bf16_t* in = vN + (size_t)bh * NTOK * HD;
    bf16_t* out = vT + (size_t)bh * NTOK * HD;
    const int tid = threadIdx.x, c = tid & 63, r4 = tid >> 6;
#pragma unroll
    for (int rr = 0; rr < 64; rr += 4)
        t[rr + r4][c] = in[(size_t)(n0 + rr + r4) * HD + d0 + c];
    __syncthreads();
#pragma unroll
    for (int rr = 0; rr < 64; rr += 4) {
        int dd = rr + r4;
        out[(size_t)(d0 + dd) * NTOK + n0 + c] = t[c][dd];
    }
}

// ---------------- flash attention: 4 waves x 32 q-rows, 32x32 MFMA ----------------
__global__ __launch_bounds__(256, 2) void attn_kernel(const bf16_t* __restrict__ qT,
                                                      const bf16_t* __restrict__ kT,
                                                      const bf16_t* __restrict__ vT,
                                                      bf16_t* __restrict__ outp) {
    __shared__ __align__(16) char lds[2][32768];  // per buf: K tile 16KB | V tile 16KB
    const int B = blockIdx.x;
    const int xcd = B & 7, jj = B >> 3;
    const int bh = xcd * 4 + (jj >> 4);
    const int q0 = (jj & 15) * 128;
    const int tid = threadIdx.x, wid = tid >> 6, lane = tid & 63;
    const int ql = lane & 31, hi = lane >> 5;

    const bf16_t* Q = qT + (size_t)bh * NTOK * HD;
    const char* Kb = (const char*)(kT + (size_t)bh * NTOK * HD);
    const char* Vb = (const char*)(vT + (size_t)bh * NTOK * HD);

    bf16x8 qf[8];
    {
        const bf16_t* qrow = Q + (size_t)(q0 + wid * 32 + ql) * HD + hi * 8;
#pragma unroll
        for (int kc = 0; kc < 8; ++kc) qf[kc] = *(const bf16x8*)(qrow + kc * 16);
    }
    f32x16 oa[4];
#pragma unroll
    for (int df = 0; df < 4; ++df)
#pragma unroll
        for (int r = 0; r < 16; ++r) oa[df][r] = 0.f;
    float m_run = -1e30f, l_run = 0.f;

    auto stage = [&](int t, int buf) {
#pragma unroll
        for (int i = 0; i < 4; ++i) {
            int a = wid * 4096 + i * 1024 + lane * 16;
            int row = a >> 8;
            int col = (a & 255) ^ ((row & 7) << 4);
            gload16(Kb + (size_t)(t * 64 + row) * 256 + col,
                    (char*)lds[buf] + wid * 4096 + i * 1024);
        }
#pragma unroll
        for (int i = 0; i < 4; ++i) {
            int a = wid * 4096 + i * 1024 + lane * 16;
            int row = a >> 7;
            int col = (a & 127) ^ ((row & 7) << 4);
            gload16(Vb + (size_t)row * (NTOK * 2) + t * 128 + col,
                    (char*)lds[buf] + 16384 + wid * 4096 + i * 1024);
        }
    };
    stage(0, 0);
    __syncthreads();

    for (int t = 0; t < NTOK / 64; ++t) {
        if (t < NTOK / 64 - 1) stage(t + 1, (t + 1) & 1);
        const char* Kl = lds[t & 1];
        const char* Vl = Kl + 16384;

        f32x16 s[2];
#pragma unroll
        for (int nb = 0; nb < 2; ++nb) {
#pragma unroll
            for (int r = 0; r < 16; ++r) s[nb][r] = 0.f;
            int row = nb * 32 + ql;
            const char* krow = Kl + row * 256;
            int sw = (row & 7) << 4;
#pragma unroll
            for (int kc = 0; kc < 8; ++kc) {
                bf16x8 kf = *(const bf16x8*)(krow + ((kc * 32 + hi * 16) ^ sw));
                s[nb] = __builtin_amdgcn_mfma_f32_32x32x16_bf16(kf, qf[kc], s[nb], 0, 0, 0);
            }
        }

        float mx = s[0][0];
#pragma unroll
        for (int r = 1; r < 16; ++r) mx = fmaxf(mx, s[0][r]);
#pragma unroll
        for (int r = 0; r < 16; ++r) mx = fmaxf(mx, s[1][r]);
        mx = fmaxf(mx, __shfl_xor(mx, 32));
        if (__any(mx - m_run > 8.f)) {
            float mn = fmaxf(m_run, mx);
            float resc = __expf(m_run - mn);
            l_run *= resc;
#pragma unroll
            for (int df = 0; df < 4; ++df) oa[df] *= resc;
            m_run = mn;
        }
        float rs = 0.f;
#pragma unroll
        for (int nb = 0; nb < 2; ++nb)
#pragma unroll
            for (int r = 0; r < 16; ++r) {
                float e = __expf(s[nb][r] - m_run);
                s[nb][r] = e;
                rs += e;
            }
        rs += __shfl_xor(rs, 32);
        l_run += rs;

        unsigned int pk[2][8];
#pragma unroll
        for (int nb = 0; nb < 2; ++nb)
#pragma unroll
            for (int m = 0; m < 8; ++m) pk[nb][m] = pack2bf(s[nb][2 * m], s[nb][2 * m + 1]);

#pragma unroll
        for (int kc2 = 0; kc2 < 4; ++kc2) {
            const int nb = kc2 >> 1, c1 = kc2 & 1;
            union { unsigned int u[4]; bf16x8 v; } pb;
#pragma unroll
            for (int j = 0; j < 4; ++j) {
                const int bsel = (j & 1) + 4 * c1;
                unsigned int vlo = pk[nb][bsel];
                unsigned int vhi = pk[nb][bsel + 2];
                unsigned int mine = hi ? vhi : vlo;
                unsigned int yours = hi ? vlo : vhi;
                unsigned int x = (unsigned int)__shfl_xor((int)yours, 32);
                pb.u[j] = (hi == (j >> 1)) ? mine : x;
            }
#pragma unroll
            for (int df = 0; df < 4; ++df) {
                int row = df * 32 + ql;
                bf16x8 va = *(const bf16x8*)(Vl + row * 128 + ((kc2 * 32 + hi * 16) ^ ((row & 7) << 4)));
                oa[df] = __builtin_amdgcn_mfma_f32_32x32x16_bf16(va, pb.v, oa[df], 0, 0, 0);
            }
        }
        __syncthreads();
    }

    float inv = 1.f / l_run;
    bf16_t* Ot = (bf16_t*)((char*)lds + wid * 8704);
#pragma unroll
    for (int df = 0; df < 4; ++df)
#pragma unroll
        for (int rg = 0; rg < 4; ++rg) {
            bf16x4 w;
#pragma unroll
            for (int i = 0; i < 4; ++i) w[i] = (bf16_t)(oa[df][rg * 4 + i] * inv);
            int d0 = df * 32 + rg * 8 + hi * 4;
            *(bf16x4*)&Ot[ql * 136 + d0] = w;
        }
    __builtin_amdgcn_s_waitcnt(0);
    const int qloc = lane >> 1, half = lane & 1;
    const int b = bh >> 4, h = bh & 15;
    bf16_t* orow = outp + (size_t)(b * NTOK + q0 + wid * 32 + qloc) * HIDDEN + h * HD + half * 64;
    const bf16_t* src = Ot + qloc * 136 + half * 64;
#pragma unroll
    for (int c = 0; c < 8; ++c)
        *(bf16x8*)(orow + c * 8) = *(const bf16x8*)(src + c * 8);
}

extern "C" void kernel_launch(void* const* d_in, const int* in_sizes, int n_in,
                              void* d_out, int out_size, void* d_ws, size_t ws_size,
                              hipStream_t stream) {
    const float* x = (const float*)d_in[0];
    const float* w_qkv = (const float*)d_in[1];
    const float* b_qkv = (const float*)d_in[2];
    const float* w_proj = (const float*)d_in[3];
    const float* b_proj = (const float*)d_in[4];
    const int* Hp = (const int*)d_in[6];
    const int* Wp = (const int*)d_in[7];
    float* out = (float*)d_out;

    char* ws = (char*)d_ws;
    bf16_t* xb = (bf16_t*)(ws + 0);                       // 16 MiB  [4096][2048]
    bf16_t* wqkvT = (bf16_t*)(ws + 16777216);             // 24 MiB  [6144][2048]
    bf16_t* wprojT = (bf16_t*)(ws + 41943040);            // 8 MiB   [2048][2048]
    bf16_t* qkv = (bf16_t*)(ws + 50331648);               // 48 MiB  [4096][6144]
    bf16_t* qTb = (bf16_t*)(ws + 100663296);              // 16 MiB  [32][2048][128]
    bf16_t* kTb = (bf16_t*)(ws + 117440512);              // 16 MiB
    bf16_t* vN = (bf16_t*)(ws + 0);                       // reuse xb region after gemm1
    bf16_t* vT = (bf16_t*)(ws + 16777216);                // reuse wqkvT region
    bf16_t* attno = (bf16_t*)(ws + 50331648);             // reuse qkv region after rope

    cvt8_kernel<<<4096, 256, 0, stream>>>(x, xb, 1048576);
    cvtT_kernel<<<dim3(96, 32), 256, 0, stream>>>(w_qkv, wqkvT, 2048, 6144);
    cvtT_kernel<<<dim3(32, 32), 256, 0, stream>>>(w_proj, wprojT, 2048, 2048);
    gemm_pipe<bf16_t><<<768, 256, 0, stream>>>(xb, wqkvT, b_qkv, qkv, MROWS, QKVCOLS, HIDDEN);
    rope_kernel<<<4096, 256, 0, stream>>>(qkv, qTb, kTb, vN, Hp, Wp);
    transpose_v<<<dim3(2, 32, 32), 256, 0, stream>>>(vN, vT);
    attn_kernel<<<512, 256, 0, stream>>>(qTb, kTb, vT, attno);
    gemm_pipe<float><<<256, 256, 0, stream>>>(attno, wprojT, b_proj, out, MROWS, HIDDEN, HIDDEN);
}